// Round 12
// baseline (147.048 us; speedup 1.0000x reference)
//
#include <hip/hip_runtime.h>
#include <hip/hip_bf16.h>
#include <hip/hip_fp16.h>

// N=100000, K=16, H=128 graph-MLP + global softmax.
// Identities:
//  stage(f)[n] = [r_sum[n], K*f[n] - sum_k f[nb]] @ W + K*b
//  prep: vv[n] = {rsum[5], 16*p[n]-sum p[nb]}  (4 threads/node, coalesced rmat)
//  gemm2: f1 = relu(vv@W1+16b1) computed ON THE FLY (fp16, w1/b1 in LDS),
//         A = f1@W2h via fp16 MFMA (swapped operands), stored fp8 e4m3.
//  D[n] = rsum@W2r + 16*b2 + 16*A[n]   (folded into gather2)
//  f2 = relu(D - sum_k A[nb]) ; s[n] = f2 . w3h  (f2 never materialized)
//  tail (fused): logits in REGISTERS + global max + expsum + scale via
//  device-scope atomic barriers (391 blocks co-resident on 256 CUs -> safe).
// Numerics: softmax top-gap ~47 (abs err observed 1.6e-20) -> fp8/fp16 free.
// gather2: 4 nodes/iter, 34 loads, 60 VGPR, 8 waves/SIMD (R10: bigger = cliff).

#define NN 100000
#define KK 16
#define HH 128
#define NBLK ((NN + 255) / 256)   // 391 tail blocks

typedef _Float16 half8 __attribute__((ext_vector_type(8)));
typedef float f32x4 __attribute__((ext_vector_type(4)));
typedef float f32x2 __attribute__((ext_vector_type(2)));

// ------- prep: vv[n*8+{0..4}] = rsum, vv[n*8+5] = 16*p[n]-sum p[nb] ----------
// 4 threads per node; each 4-lane group reads 64B-contiguous chunks (coalesced).
// Also zero-inits the softmax semaphores/counters (no memset dispatch).
__global__ __launch_bounds__(256) void prep_kernel(
    const float* __restrict__ p, const float* __restrict__ rmat,
    const int* __restrict__ idx, float* __restrict__ vv,
    unsigned int* __restrict__ sem) {   // sem: [0]=maxkey [1]=cnt0 [2]=cnt1 [3]=sum(f32)
  const int tid = threadIdx.x;
  if (blockIdx.x == 0 && tid < 4) sem[tid] = 0u;
  const int sub = tid & 3;
  const int n = blockIdx.x * 64 + (tid >> 2);
  if (n >= NN) return;
  const float4* rr = (const float4*)(rmat) + (size_t)n * 20;
  float t[5] = {0.f, 0.f, 0.f, 0.f, 0.f};
#pragma unroll
  for (int j = 0; j < 5; ++j) {
    const float4 q = rr[sub + 4 * j];
    t[(j + 0) % 5] += q.x;
    t[(j + 1) % 5] += q.y;
    t[(j + 2) % 5] += q.z;
    t[(j + 3) % 5] += q.w;
  }
  // remap class -> col: rs[c] = t[(c + sub) % 5]  (compile-time indices only)
  float rs[5];
#pragma unroll
  for (int c = 0; c < 5; ++c) {
    float v = t[c];
    v = (sub == 1) ? t[(c + 1) % 5] : v;
    v = (sub == 2) ? t[(c + 2) % 5] : v;
    v = (sub == 3) ? t[(c + 3) % 5] : v;
    rs[c] = v;
  }
  const int* nb = idx + (size_t)n * 17 + 1;
  float ps = 0.f;
#pragma unroll
  for (int k = 0; k < 4; ++k) ps += p[nb[sub * 4 + k]];
#pragma unroll
  for (int c = 0; c < 5; ++c) {
    rs[c] += __shfl_xor(rs[c], 1, 64);
    rs[c] += __shfl_xor(rs[c], 2, 64);
  }
  ps += __shfl_xor(ps, 1, 64);
  ps += __shfl_xor(ps, 2, 64);
  if (sub == 0) {
    float4 lo; lo.x = rs[0]; lo.y = rs[1]; lo.z = rs[2]; lo.w = rs[3];
    *(float4*)&vv[(size_t)n * 8] = lo;
  } else if (sub == 1) {
    float4 hi; hi.x = rs[4]; hi.y = 16.f * p[n] - ps; hi.z = 0.f; hi.w = 0.f;
    *(float4*)&vv[(size_t)n * 8 + 4] = hi;
  }
}

// ------- gemm2: A8 = fp8( relu(vv@W1+16b1) @ W2h ) --------------------------
__global__ __launch_bounds__(256, 2) void gemm2_kernel(
    const float* __restrict__ vv, const float* __restrict__ w1,
    const float* __restrict__ b1, const float* __restrict__ w2,
    unsigned char* __restrict__ A8) {
  __shared__ __align__(16) _Float16 s_w1[6][128];
  __shared__ __align__(16) _Float16 s_b1[128];
  const int tid = threadIdx.x;
  if (tid < 128) {
#pragma unroll
    for (int c = 0; c < 6; ++c) s_w1[c][tid] = (_Float16)w1[c * HH + tid];
    s_b1[tid] = (_Float16)(16.f * b1[tid]);
  }
  const int lane = tid & 63;
  const int wgl = (blockIdx.x << 2) + (tid >> 6);
  const int colhalf = wgl & 1;            // output cols colhalf*64 .. +63
  const int strip0 = wgl >> 1;
  const int sstride = (gridDim.x << 2) >> 1;
  const int r16 = lane & 15;
  const int g16 = lane >> 4;              // 0..3

  half8 wfrag[4][4];                       // [ct][kk] of W2h^T
#pragma unroll
  for (int ct = 0; ct < 4; ++ct) {
#pragma unroll
    for (int kk = 0; kk < 4; ++kk) {
      const int hcol = colhalf * 64 + ct * 16 + r16;
#pragma unroll
      for (int e = 0; e < 8; ++e)
        wfrag[ct][kk][e] = (_Float16)w2[(size_t)(5 + kk * 32 + g16 * 8 + e) * HH + hcol];
    }
  }
  __syncthreads();   // s_w1/s_b1 ready; LDS is read-only from here on

  for (int strip = strip0; strip < NN / 16; strip += sstride) {
    const int nbase = strip * 16;
    const float* vr = vv + (size_t)(nbase + r16) * 8;
    const float4 vlo = *(const float4*)vr;
    const float4 vhi = *(const float4*)(vr + 4);
    const _Float16 x0 = (_Float16)vlo.x, x1 = (_Float16)vlo.y,
                   x2 = (_Float16)vlo.z, x3 = (_Float16)vlo.w,
                   x4 = (_Float16)vhi.x, x5 = (_Float16)vhi.y;
    half8 xfrag[4];
#pragma unroll
    for (int kk = 0; kk < 4; ++kk) {
      const int off = kk * 32 + g16 * 8;
      half8 a = *(const half8*)&s_b1[off];
      const half8 w0 = *(const half8*)&s_w1[0][off];
      const half8 w1v = *(const half8*)&s_w1[1][off];
      const half8 w2v = *(const half8*)&s_w1[2][off];
      const half8 w3v = *(const half8*)&s_w1[3][off];
      const half8 w4v = *(const half8*)&s_w1[4][off];
      const half8 w5v = *(const half8*)&s_w1[5][off];
#pragma unroll
      for (int e = 0; e < 8; ++e) {
        _Float16 v = a[e] + w0[e] * x0 + w1v[e] * x1 + w2v[e] * x2
                   + w3v[e] * x3 + w4v[e] * x4 + w5v[e] * x5;
        a[e] = v > (_Float16)0.f ? v : (_Float16)0.f;
      }
      xfrag[kk] = a;
    }
    f32x4 acc[4] = {{0.f,0.f,0.f,0.f},{0.f,0.f,0.f,0.f},{0.f,0.f,0.f,0.f},{0.f,0.f,0.f,0.f}};
#pragma unroll
    for (int kk = 0; kk < 4; ++kk) {
#pragma unroll
      for (int ct = 0; ct < 4; ++ct)
        acc[ct] = __builtin_amdgcn_mfma_f32_16x16x32_f16(wfrag[ct][kk], xfrag[kk], acc[ct], 0, 0, 0);
    }
#pragma unroll
    for (int ct = 0; ct < 4; ++ct) {
      int packed = __builtin_amdgcn_cvt_pk_fp8_f32(acc[ct][0], acc[ct][1], 0, false);
      packed = __builtin_amdgcn_cvt_pk_fp8_f32(acc[ct][2], acc[ct][3], packed, true);
      *(int*)&A8[(size_t)(nbase + r16) * HH + colhalf * 64 + ct * 16 + g16 * 4] = packed;
    }
  }
}

// ---------------- gather2: s[n] = relu(D[n] - sum_k A[nb]) . w3h --------------
// 4 nodes per wave-iteration: 34 loads in flight (proven sweet spot).
#define REDUCE_PAIR(NBASE, AV0, AV1, DRAW)                                    \
  {                                                                           \
    f32x2 s0l = {0.f,0.f}, s0h = {0.f,0.f}, s1l = {0.f,0.f}, s1h = {0.f,0.f};\
    _Pragma("unroll")                                                         \
    for (int pp = 0; pp < 8; ++pp) {                                          \
      s0l -= __builtin_amdgcn_cvt_pk_f32_fp8(AV0[pp], false);                 \
      s0h -= __builtin_amdgcn_cvt_pk_f32_fp8(AV0[pp], true);                  \
      s1l -= __builtin_amdgcn_cvt_pk_f32_fp8(AV1[pp], false);                 \
      s1h -= __builtin_amdgcn_cvt_pk_f32_fp8(AV1[pp], true);                  \
    }                                                                         \
    {                                                                         \
      const int nd = (NBASE) + half;                                          \
      f32x2 dl = b2l + __builtin_amdgcn_cvt_pk_f32_fp8(DRAW, false);          \
      f32x2 dh = b2h + __builtin_amdgcn_cvt_pk_f32_fp8(DRAW, true);           \
      dl *= 16.f; dh *= 16.f;                                                 \
      const float* vr = vv + (size_t)nd * 8;                                  \
      _Pragma("unroll")                                                       \
      for (int j = 0; j < 5; ++j) {                                           \
        const float r = vr[j];                                                \
        dl += r * w2rl[j]; dh += r * w2rh[j];                                 \
      }                                                                       \
      if (half == 0) { s0l += dl; s0h += dh; }                                \
      else           { s1l += dl; s1h += dh; }                                \
    }                                                                         \
    s0l[0] += __shfl_xor(s0l[0], 32, 64); s0l[1] += __shfl_xor(s0l[1], 32, 64);\
    s0h[0] += __shfl_xor(s0h[0], 32, 64); s0h[1] += __shfl_xor(s0h[1], 32, 64);\
    s1l[0] += __shfl_xor(s1l[0], 32, 64); s1l[1] += __shfl_xor(s1l[1], 32, 64);\
    s1h[0] += __shfl_xor(s1h[0], 32, 64); s1h[1] += __shfl_xor(s1h[1], 32, 64);\
    float v0 = fmaxf(s0l[0], 0.f) * w3l[0] + fmaxf(s0l[1], 0.f) * w3l[1]      \
             + fmaxf(s0h[0], 0.f) * w3h[0] + fmaxf(s0h[1], 0.f) * w3h[1];     \
    float v1 = fmaxf(s1l[0], 0.f) * w3l[0] + fmaxf(s1l[1], 0.f) * w3l[1]      \
             + fmaxf(s1h[0], 0.f) * w3h[0] + fmaxf(s1h[1], 0.f) * w3h[1];     \
    _Pragma("unroll")                                                         \
    for (int off = 16; off > 0; off >>= 1) {                                  \
      v0 += __shfl_xor(v0, off, 64);                                          \
      v1 += __shfl_xor(v1, off, 64);                                          \
    }                                                                         \
    if (lane == 0) { sv[(NBASE)] = v0; sv[(NBASE) + 1] = v1; }                \
  }

__global__ __launch_bounds__(256) void gather2_kernel(
    const unsigned char* __restrict__ A8, const float* __restrict__ vv,
    const float* __restrict__ w2, const float* __restrict__ b2,
    const float* __restrict__ w3, const int* __restrict__ idx,
    float* __restrict__ sv) {
  const int lane = threadIdx.x & 63;
  const int half = lane >> 5;       // 0/1: even/odd neighbors
  const int q = lane & 31;          // cols 4q..4q+3
  const int wid = (blockIdx.x << 2) + (threadIdx.x >> 6);
  const int nwaves = gridDim.x << 2;
  const f32x2 w3l = {w3[5 + 4 * q], w3[6 + 4 * q]};
  const f32x2 w3h = {w3[7 + 4 * q], w3[8 + 4 * q]};
  f32x2 w2rl[5], w2rh[5];
#pragma unroll
  for (int j = 0; j < 5; ++j) {
    w2rl[j] = *(const f32x2*)&w2[j * 128 + (q << 2)];
    w2rh[j] = *(const f32x2*)&w2[j * 128 + (q << 2) + 2];
  }
  const f32x2 b2l = *(const f32x2*)&b2[(q << 2)];
  const f32x2 b2h = *(const f32x2*)&b2[(q << 2) + 2];

  for (int t = wid; t < NN / 4; t += nwaves) {
    const int n = t * 4;
    const int* nb = idx + (size_t)n * 17 + 1;
    unsigned int avA[8], avB[8], avC[8], avD[8];
#pragma unroll
    for (int pp = 0; pp < 8; ++pp) {
      const int k = 2 * pp + half;
      avA[pp] = *(const unsigned int*)&A8[(size_t)nb[k]      * HH + (q << 2)];
      avB[pp] = *(const unsigned int*)&A8[(size_t)nb[17 + k] * HH + (q << 2)];
    }
    const unsigned int dAB = *(const unsigned int*)&A8[(size_t)(n + half) * HH + (q << 2)];
#pragma unroll
    for (int pp = 0; pp < 8; ++pp) {
      const int k = 2 * pp + half;
      avC[pp] = *(const unsigned int*)&A8[(size_t)nb[34 + k] * HH + (q << 2)];
      avD[pp] = *(const unsigned int*)&A8[(size_t)nb[51 + k] * HH + (q << 2)];
    }
    const unsigned int dCD = *(const unsigned int*)&A8[(size_t)(n + 2 + half) * HH + (q << 2)];
    REDUCE_PAIR(n, avA, avB, dAB)
    REDUCE_PAIR(n + 2, avC, avD, dCD)
  }
}

// ---- monotone uint key for float atomic-max --------------------------------
__device__ __forceinline__ unsigned int fkey(float f) {
  unsigned int b = __float_as_uint(f);
  return (b & 0x80000000u) ? ~b : (b | 0x80000000u);
}

// ------ tail: logits (in regs) + global max + expsum + scale, one kernel -----
// 391 blocks, all co-resident (256 CUs) -> device-scope atomic barriers safe.
__global__ __launch_bounds__(256) void tail_kernel(
    const float* __restrict__ sv, const float* __restrict__ vv,
    const float* __restrict__ w3, const float* __restrict__ b3,
    const int* __restrict__ idx, float* __restrict__ out,
    unsigned int* __restrict__ sem) {  // [0]=maxkey [1]=cnt0 [2]=cnt1 [3]=sum(f32)
  __shared__ float s[256];
  __shared__ float sh_bcast;
  const int tid = threadIdx.x;
  const int n = blockIdx.x * 256 + tid;
  float t = -3.4e38f;
  if (n < NN) {
    t = 16.f * sv[n];
    const int* nb = idx + (size_t)n * 17 + 1;
#pragma unroll
    for (int k = 0; k < KK; ++k) t -= sv[nb[k]];
#pragma unroll
    for (int c = 0; c < 5; ++c) t += vv[(size_t)n * 8 + c] * w3[c];
    t += 16.f * b3[0];
  }
  // block max -> global atomicMax -> barrier 1 -> read global max
  s[tid] = t; __syncthreads();
  for (int off = 128; off > 0; off >>= 1) {
    if (tid < off) s[tid] = fmaxf(s[tid], s[tid + off]);
    __syncthreads();
  }
  if (tid == 0) {
    atomicMax(&sem[0], fkey(s[0]));
    __threadfence();
    atomicAdd(&sem[1], 1u);
    while (atomicAdd(&sem[1], 0u) < (unsigned)NBLK) { __builtin_amdgcn_s_sleep(8); }
    const unsigned int k = atomicAdd(&sem[0], 0u);
    sh_bcast = __uint_as_float((k & 0x80000000u) ? (k & 0x7FFFFFFFu) : ~k);
  }
  __syncthreads();
  const float m = sh_bcast;
  const float e = (n < NN) ? __expf(t - m) : 0.f;
  // block sum -> global atomicAdd -> barrier 2 -> read global sum
  __syncthreads();   // s[] reuse
  s[tid] = e; __syncthreads();
  for (int off = 128; off > 0; off >>= 1) {
    if (tid < off) s[tid] += s[tid + off];
    __syncthreads();
  }
  if (tid == 0) {
    atomicAdd((float*)&sem[3], s[0]);
    __threadfence();
    atomicAdd(&sem[2], 1u);
    while (atomicAdd(&sem[2], 0u) < (unsigned)NBLK) { __builtin_amdgcn_s_sleep(8); }
    sh_bcast = 1.f / atomicAdd((float*)&sem[3], 0.f);
  }
  __syncthreads();
  if (n < NN) out[n] = e * sh_bcast;
}

extern "C" void kernel_launch(void* const* d_in, const int* in_sizes, int n_in,
                              void* d_out, int out_size, void* d_ws, size_t ws_size,
                              hipStream_t stream) {
  const float* p    = (const float*)d_in[0];
  const float* rmat = (const float*)d_in[1];
  const float* w1   = (const float*)d_in[2];
  const float* b1   = (const float*)d_in[3];
  const float* w2   = (const float*)d_in[4];
  const float* b2   = (const float*)d_in[5];
  const float* w3   = (const float*)d_in[6];
  const float* b3   = (const float*)d_in[7];
  const int*   idx  = (const int*)d_in[8];
  float* out = (float*)d_out;
  float* ws = (float*)d_ws;

  float* vv = ws;                                        // N*8 f32
  unsigned char* A8 = (unsigned char*)(ws + (size_t)NN * 8); // N*128 fp8
  float* sv  = (float*)(A8 + (size_t)NN * HH);           // N
  unsigned int* sem = (unsigned int*)(sv + NN);          // [0]=maxkey [1]=cnt0 [2]=cnt1 [3]=sum

  prep_kernel<<<(NN + 63) / 64, 256, 0, stream>>>(p, rmat, idx, vv, sem);
  gemm2_kernel<<<1024, 256, 0, stream>>>(vv, w1, b1, w2, A8);
  gather2_kernel<<<2048, 256, 0, stream>>>(A8, vv, w2, b2, w3, idx, sv);
  tail_kernel<<<NBLK, 256, 0, stream>>>(sv, vv, w3, b3, idx, out, sem);
}

// Round 13
// 82.687 us; speedup vs baseline: 1.7784x; 1.7784x over previous
//
#include <hip/hip_runtime.h>
#include <hip/hip_bf16.h>
#include <hip/hip_fp16.h>

// N=100000, K=16, H=128 graph-MLP + global softmax.
// Identities:
//  stage(f)[n] = [r_sum[n], K*f[n] - sum_k f[nb]] @ W + K*b
//  prep: vv[n] = {rsum[5], 16*p[n]-sum p[nb]}  (4 threads/node, coalesced rmat)
//  gemm2: f1 = relu(vv@W1+16b1) computed ON THE FLY (fp16, w1/b1 in LDS),
//         A = f1@W2h via fp16 MFMA (swapped operands), stored fp8 e4m3.
//  D[n] = rsum@W2r + 16*b2 + 16*A[n]   (folded into gather2)
//  f2 = relu(D - sum_k A[nb]) ; s[n] = f2 . w3h  (f2 never materialized)
//  logits[n] = 16*s[n] - sum_k s[nb] + rsum.w3r + 16*b3
// Numerics: softmax top-gap ~47 (abs err observed 1.6e-20) -> fp8/fp16 free.
// gather2: 4 nodes/iter, 34 loads, 60 VGPR, 8 waves/SIMD (R10: bigger = cliff).
// Softmax tail: 3 small launches with one-shot atomics (R12: fused spin-barrier
// tail = 80 us of cross-XCD semaphore ping-pong -- never again).

#define NN 100000
#define KK 16
#define HH 128

typedef _Float16 half8 __attribute__((ext_vector_type(8)));
typedef float f32x4 __attribute__((ext_vector_type(4)));
typedef float f32x2 __attribute__((ext_vector_type(2)));

// ------- prep: vv[n*8+{0..4}] = rsum, vv[n*8+5] = 16*p[n]-sum p[nb] ----------
// 4 threads per node; each 4-lane group reads 64B-contiguous chunks (coalesced).
// Also zero-inits the softmax accumulators (no memset dispatch).
__global__ __launch_bounds__(256) void prep_kernel(
    const float* __restrict__ p, const float* __restrict__ rmat,
    const int* __restrict__ idx, float* __restrict__ vv,
    unsigned int* __restrict__ sem) {   // sem: [0]=maxkey [1]=sum(f32)
  const int tid = threadIdx.x;
  if (blockIdx.x == 0 && tid < 2) sem[tid] = 0u;
  const int sub = tid & 3;
  const int n = blockIdx.x * 64 + (tid >> 2);
  if (n >= NN) return;
  const float4* rr = (const float4*)(rmat) + (size_t)n * 20;
  float t[5] = {0.f, 0.f, 0.f, 0.f, 0.f};
#pragma unroll
  for (int j = 0; j < 5; ++j) {
    const float4 q = rr[sub + 4 * j];
    t[(j + 0) % 5] += q.x;
    t[(j + 1) % 5] += q.y;
    t[(j + 2) % 5] += q.z;
    t[(j + 3) % 5] += q.w;
  }
  // remap class -> col: rs[c] = t[(c + sub) % 5]  (compile-time indices only)
  float rs[5];
#pragma unroll
  for (int c = 0; c < 5; ++c) {
    float v = t[c];
    v = (sub == 1) ? t[(c + 1) % 5] : v;
    v = (sub == 2) ? t[(c + 2) % 5] : v;
    v = (sub == 3) ? t[(c + 3) % 5] : v;
    rs[c] = v;
  }
  const int* nb = idx + (size_t)n * 17 + 1;
  float ps = 0.f;
#pragma unroll
  for (int k = 0; k < 4; ++k) ps += p[nb[sub * 4 + k]];
#pragma unroll
  for (int c = 0; c < 5; ++c) {
    rs[c] += __shfl_xor(rs[c], 1, 64);
    rs[c] += __shfl_xor(rs[c], 2, 64);
  }
  ps += __shfl_xor(ps, 1, 64);
  ps += __shfl_xor(ps, 2, 64);
  if (sub == 0) {
    float4 lo; lo.x = rs[0]; lo.y = rs[1]; lo.z = rs[2]; lo.w = rs[3];
    *(float4*)&vv[(size_t)n * 8] = lo;
  } else if (sub == 1) {
    float4 hi; hi.x = rs[4]; hi.y = 16.f * p[n] - ps; hi.z = 0.f; hi.w = 0.f;
    *(float4*)&vv[(size_t)n * 8 + 4] = hi;
  }
}

// ------- gemm2: A8 = fp8( relu(vv@W1+16b1) @ W2h ) --------------------------
__global__ __launch_bounds__(256, 2) void gemm2_kernel(
    const float* __restrict__ vv, const float* __restrict__ w1,
    const float* __restrict__ b1, const float* __restrict__ w2,
    unsigned char* __restrict__ A8) {
  __shared__ __align__(16) _Float16 s_w1[6][128];
  __shared__ __align__(16) _Float16 s_b1[128];
  const int tid = threadIdx.x;
  if (tid < 128) {
#pragma unroll
    for (int c = 0; c < 6; ++c) s_w1[c][tid] = (_Float16)w1[c * HH + tid];
    s_b1[tid] = (_Float16)(16.f * b1[tid]);
  }
  const int lane = tid & 63;
  const int wgl = (blockIdx.x << 2) + (tid >> 6);
  const int colhalf = wgl & 1;            // output cols colhalf*64 .. +63
  const int strip0 = wgl >> 1;
  const int sstride = (gridDim.x << 2) >> 1;
  const int r16 = lane & 15;
  const int g16 = lane >> 4;              // 0..3

  half8 wfrag[4][4];                       // [ct][kk] of W2h^T
#pragma unroll
  for (int ct = 0; ct < 4; ++ct) {
#pragma unroll
    for (int kk = 0; kk < 4; ++kk) {
      const int hcol = colhalf * 64 + ct * 16 + r16;
#pragma unroll
      for (int e = 0; e < 8; ++e)
        wfrag[ct][kk][e] = (_Float16)w2[(size_t)(5 + kk * 32 + g16 * 8 + e) * HH + hcol];
    }
  }
  __syncthreads();   // s_w1/s_b1 ready; LDS is read-only from here on

  for (int strip = strip0; strip < NN / 16; strip += sstride) {
    const int nbase = strip * 16;
    const float* vr = vv + (size_t)(nbase + r16) * 8;
    const float4 vlo = *(const float4*)vr;
    const float4 vhi = *(const float4*)(vr + 4);
    const _Float16 x0 = (_Float16)vlo.x, x1 = (_Float16)vlo.y,
                   x2 = (_Float16)vlo.z, x3 = (_Float16)vlo.w,
                   x4 = (_Float16)vhi.x, x5 = (_Float16)vhi.y;
    half8 xfrag[4];
#pragma unroll
    for (int kk = 0; kk < 4; ++kk) {
      const int off = kk * 32 + g16 * 8;
      half8 a = *(const half8*)&s_b1[off];
      const half8 w0 = *(const half8*)&s_w1[0][off];
      const half8 w1v = *(const half8*)&s_w1[1][off];
      const half8 w2v = *(const half8*)&s_w1[2][off];
      const half8 w3v = *(const half8*)&s_w1[3][off];
      const half8 w4v = *(const half8*)&s_w1[4][off];
      const half8 w5v = *(const half8*)&s_w1[5][off];
#pragma unroll
      for (int e = 0; e < 8; ++e) {
        _Float16 v = a[e] + w0[e] * x0 + w1v[e] * x1 + w2v[e] * x2
                   + w3v[e] * x3 + w4v[e] * x4 + w5v[e] * x5;
        a[e] = v > (_Float16)0.f ? v : (_Float16)0.f;
      }
      xfrag[kk] = a;
    }
    f32x4 acc[4] = {{0.f,0.f,0.f,0.f},{0.f,0.f,0.f,0.f},{0.f,0.f,0.f,0.f},{0.f,0.f,0.f,0.f}};
#pragma unroll
    for (int kk = 0; kk < 4; ++kk) {
#pragma unroll
      for (int ct = 0; ct < 4; ++ct)
        acc[ct] = __builtin_amdgcn_mfma_f32_16x16x32_f16(wfrag[ct][kk], xfrag[kk], acc[ct], 0, 0, 0);
    }
#pragma unroll
    for (int ct = 0; ct < 4; ++ct) {
      int packed = __builtin_amdgcn_cvt_pk_fp8_f32(acc[ct][0], acc[ct][1], 0, false);
      packed = __builtin_amdgcn_cvt_pk_fp8_f32(acc[ct][2], acc[ct][3], packed, true);
      *(int*)&A8[(size_t)(nbase + r16) * HH + colhalf * 64 + ct * 16 + g16 * 4] = packed;
    }
  }
}

// ---------------- gather2: s[n] = relu(D[n] - sum_k A[nb]) . w3h --------------
// 4 nodes per wave-iteration: 34 loads in flight (proven sweet spot).
#define REDUCE_PAIR(NBASE, AV0, AV1, DRAW)                                    \
  {                                                                           \
    f32x2 s0l = {0.f,0.f}, s0h = {0.f,0.f}, s1l = {0.f,0.f}, s1h = {0.f,0.f};\
    _Pragma("unroll")                                                         \
    for (int pp = 0; pp < 8; ++pp) {                                          \
      s0l -= __builtin_amdgcn_cvt_pk_f32_fp8(AV0[pp], false);                 \
      s0h -= __builtin_amdgcn_cvt_pk_f32_fp8(AV0[pp], true);                  \
      s1l -= __builtin_amdgcn_cvt_pk_f32_fp8(AV1[pp], false);                 \
      s1h -= __builtin_amdgcn_cvt_pk_f32_fp8(AV1[pp], true);                  \
    }                                                                         \
    {                                                                         \
      const int nd = (NBASE) + half;                                          \
      f32x2 dl = b2l + __builtin_amdgcn_cvt_pk_f32_fp8(DRAW, false);          \
      f32x2 dh = b2h + __builtin_amdgcn_cvt_pk_f32_fp8(DRAW, true);           \
      dl *= 16.f; dh *= 16.f;                                                 \
      const float* vr = vv + (size_t)nd * 8;                                  \
      _Pragma("unroll")                                                       \
      for (int j = 0; j < 5; ++j) {                                           \
        const float r = vr[j];                                                \
        dl += r * w2rl[j]; dh += r * w2rh[j];                                 \
      }                                                                       \
      if (half == 0) { s0l += dl; s0h += dh; }                                \
      else           { s1l += dl; s1h += dh; }                                \
    }                                                                         \
    s0l[0] += __shfl_xor(s0l[0], 32, 64); s0l[1] += __shfl_xor(s0l[1], 32, 64);\
    s0h[0] += __shfl_xor(s0h[0], 32, 64); s0h[1] += __shfl_xor(s0h[1], 32, 64);\
    s1l[0] += __shfl_xor(s1l[0], 32, 64); s1l[1] += __shfl_xor(s1l[1], 32, 64);\
    s1h[0] += __shfl_xor(s1h[0], 32, 64); s1h[1] += __shfl_xor(s1h[1], 32, 64);\
    float v0 = fmaxf(s0l[0], 0.f) * w3l[0] + fmaxf(s0l[1], 0.f) * w3l[1]      \
             + fmaxf(s0h[0], 0.f) * w3h[0] + fmaxf(s0h[1], 0.f) * w3h[1];     \
    float v1 = fmaxf(s1l[0], 0.f) * w3l[0] + fmaxf(s1l[1], 0.f) * w3l[1]      \
             + fmaxf(s1h[0], 0.f) * w3h[0] + fmaxf(s1h[1], 0.f) * w3h[1];     \
    _Pragma("unroll")                                                         \
    for (int off = 16; off > 0; off >>= 1) {                                  \
      v0 += __shfl_xor(v0, off, 64);                                          \
      v1 += __shfl_xor(v1, off, 64);                                          \
    }                                                                         \
    if (lane == 0) { sv[(NBASE)] = v0; sv[(NBASE) + 1] = v1; }                \
  }

__global__ __launch_bounds__(256) void gather2_kernel(
    const unsigned char* __restrict__ A8, const float* __restrict__ vv,
    const float* __restrict__ w2, const float* __restrict__ b2,
    const float* __restrict__ w3, const int* __restrict__ idx,
    float* __restrict__ sv) {
  const int lane = threadIdx.x & 63;
  const int half = lane >> 5;       // 0/1: even/odd neighbors
  const int q = lane & 31;          // cols 4q..4q+3
  const int wid = (blockIdx.x << 2) + (threadIdx.x >> 6);
  const int nwaves = gridDim.x << 2;
  const f32x2 w3l = {w3[5 + 4 * q], w3[6 + 4 * q]};
  const f32x2 w3h = {w3[7 + 4 * q], w3[8 + 4 * q]};
  f32x2 w2rl[5], w2rh[5];
#pragma unroll
  for (int j = 0; j < 5; ++j) {
    w2rl[j] = *(const f32x2*)&w2[j * 128 + (q << 2)];
    w2rh[j] = *(const f32x2*)&w2[j * 128 + (q << 2) + 2];
  }
  const f32x2 b2l = *(const f32x2*)&b2[(q << 2)];
  const f32x2 b2h = *(const f32x2*)&b2[(q << 2) + 2];

  for (int t = wid; t < NN / 4; t += nwaves) {
    const int n = t * 4;
    const int* nb = idx + (size_t)n * 17 + 1;
    unsigned int avA[8], avB[8], avC[8], avD[8];
#pragma unroll
    for (int pp = 0; pp < 8; ++pp) {
      const int k = 2 * pp + half;
      avA[pp] = *(const unsigned int*)&A8[(size_t)nb[k]      * HH + (q << 2)];
      avB[pp] = *(const unsigned int*)&A8[(size_t)nb[17 + k] * HH + (q << 2)];
    }
    const unsigned int dAB = *(const unsigned int*)&A8[(size_t)(n + half) * HH + (q << 2)];
#pragma unroll
    for (int pp = 0; pp < 8; ++pp) {
      const int k = 2 * pp + half;
      avC[pp] = *(const unsigned int*)&A8[(size_t)nb[34 + k] * HH + (q << 2)];
      avD[pp] = *(const unsigned int*)&A8[(size_t)nb[51 + k] * HH + (q << 2)];
    }
    const unsigned int dCD = *(const unsigned int*)&A8[(size_t)(n + 2 + half) * HH + (q << 2)];
    REDUCE_PAIR(n, avA, avB, dAB)
    REDUCE_PAIR(n + 2, avC, avD, dCD)
  }
}

// ---- monotone uint key for float atomic-max --------------------------------
__device__ __forceinline__ unsigned int fkey(float f) {
  unsigned int b = __float_as_uint(f);
  return (b & 0x80000000u) ? ~b : (b | 0x80000000u);
}

// ------ stage3: logits + global max via atomicMax(key) ------------------------
__global__ __launch_bounds__(256) void stage3s_kernel(
    const float* __restrict__ sv, const float* __restrict__ vv,
    const float* __restrict__ w3, const float* __restrict__ b3,
    const int* __restrict__ idx, float* __restrict__ lg,
    unsigned int* __restrict__ sem) {
  __shared__ float s[256];
  const int n = blockIdx.x * 256 + threadIdx.x;
  float t = -3.4e38f;
  if (n < NN) {
    t = 16.f * sv[n];
    const int* nb = idx + (size_t)n * 17 + 1;
#pragma unroll
    for (int k = 0; k < KK; ++k) t -= sv[nb[k]];
#pragma unroll
    for (int c = 0; c < 5; ++c) t += vv[(size_t)n * 8 + c] * w3[c];
    t += 16.f * b3[0];
    lg[n] = t;
  }
  s[threadIdx.x] = t; __syncthreads();
  for (int off = 128; off > 0; off >>= 1) {
    if (threadIdx.x < off) s[threadIdx.x] = fmaxf(s[threadIdx.x], s[threadIdx.x + off]);
    __syncthreads();
  }
  if (threadIdx.x == 0) atomicMax(&sem[0], fkey(s[0]));
}

// ------ expsum: out = e^(lg-m), atomicAdd global sum --------------------------
__global__ __launch_bounds__(256) void expsum_kernel(
    const float* __restrict__ lg, const unsigned int* __restrict__ sem,
    float* __restrict__ out, float* __restrict__ pstot) {
  __shared__ float s[256];
  const int tid = threadIdx.x;
  const unsigned int k = sem[0];
  const float m = __uint_as_float((k & 0x80000000u) ? (k & 0x7FFFFFFFu) : ~k);
  float acc = 0.f;
  for (int i = blockIdx.x * 256 + tid; i < NN; i += 256 * 256) {
    float e = __expf(lg[i] - m);
    out[i] = e;
    acc += e;
  }
  s[tid] = acc; __syncthreads();
  for (int off = 128; off > 0; off >>= 1) {
    if (tid < off) s[tid] += s[tid + off];
    __syncthreads();
  }
  if (tid == 0) atomicAdd(pstot, s[0]);
}

__global__ __launch_bounds__(256) void scale_kernel(
    float* __restrict__ out, const float* __restrict__ pstot) {
  const int i = blockIdx.x * 256 + threadIdx.x;
  const float inv = 1.f / pstot[0];
  if (i < NN) out[i] *= inv;
}

extern "C" void kernel_launch(void* const* d_in, const int* in_sizes, int n_in,
                              void* d_out, int out_size, void* d_ws, size_t ws_size,
                              hipStream_t stream) {
  const float* p    = (const float*)d_in[0];
  const float* rmat = (const float*)d_in[1];
  const float* w1   = (const float*)d_in[2];
  const float* b1   = (const float*)d_in[3];
  const float* w2   = (const float*)d_in[4];
  const float* b2   = (const float*)d_in[5];
  const float* w3   = (const float*)d_in[6];
  const float* b3   = (const float*)d_in[7];
  const int*   idx  = (const int*)d_in[8];
  float* out = (float*)d_out;
  float* ws = (float*)d_ws;

  float* vv = ws;                                        // N*8 f32
  unsigned char* A8 = (unsigned char*)(ws + (size_t)NN * 8); // N*128 fp8
  float* sv  = (float*)(A8 + (size_t)NN * HH);           // N
  float* lg  = sv + NN;                                  // N
  unsigned int* sem = (unsigned int*)(lg + NN);          // [0]=maxkey [1]=sum(f32)
  float* pstot = (float*)(sem + 1);                      // aliases sem[1]

  prep_kernel<<<(NN + 63) / 64, 256, 0, stream>>>(p, rmat, idx, vv, sem);
  gemm2_kernel<<<1024, 256, 0, stream>>>(vv, w1, b1, w2, A8);
  gather2_kernel<<<2048, 256, 0, stream>>>(A8, vv, w2, b2, w3, idx, sv);
  stage3s_kernel<<<(NN + 255) / 256, 256, 0, stream>>>(sv, vv, w3, b3, idx, lg, sem);
  expsum_kernel<<<256, 256, 0, stream>>>(lg, sem, out, pstot);
  scale_kernel<<<(NN + 255) / 256, 256, 0, stream>>>(out, pstot);
}